// Round 5
// baseline (254.419 us; speedup 1.0000x reference)
//
#include <hip/hip_runtime.h>
#include <hip/hip_bf16.h>

#define HS 128
#define NVT 32
#define NN 256

typedef __attribute__((ext_vector_type(8))) short bf16x8;
typedef __attribute__((ext_vector_type(4))) float f32x4;

// ws layout (bytes):
//   [0, 32768)        TABB bf16 [512][32]: rows 0..383 = GW[t][g] at [g][t]; rows 384..511 = G[t][h] at [384+h][t]
//   [32768, 57344)    GIT  bf16 [32][384]
//   [65536, 16842752) cnt8 u8 [512][4][256][32]  per-chunk partial histograms
#define TABB_OFF 0
#define GIT_OFF  32768
#define CNT8_OFF 65536

static __device__ __forceinline__ short f2bs(float f) {
    __hip_bfloat16 h = __float2bfloat16(f);
    short s; __builtin_memcpy(&s, &h, 2);
    return s;
}
static __device__ __forceinline__ float bs2f(short s) {
    __hip_bfloat16 h; __builtin_memcpy(&h, &s, 2);
    return __bfloat162float(h);
}
static __device__ __forceinline__ float sigm(float x) {
    return __builtin_amdgcn_rcpf(1.f + __expf(-x));
}

// ---------------- Kernel A: tiny tables (fp32 inputs) -----------------------
__global__ void __launch_bounds__(512) build_tables(
    const float* __restrict__ W_ih, const float* __restrict__ W_hh,
    const float* __restrict__ b_ih, const float* __restrict__ b_hh,
    const float* __restrict__ Wg,   const float* __restrict__ bg,
    const float* __restrict__ Wm,
    short* __restrict__ TABB, short* __restrict__ GIT)
{
    __shared__ float G_s[HS];
    const int t = blockIdx.x;
    const int j = threadIdx.x;
    if (j < HS) {
        float x = Wg[j * NVT + t] + bg[j];
        G_s[j] = sigm(x) * Wm[j * NVT + t];
    }
    __syncthreads();
    if (j < 384) {
        float acc = 0.f;
        for (int h = 0; h < HS; ++h) acc += G_s[h] * W_hh[j * HS + h];
        TABB[j * NVT + t] = f2bs(acc);
        float git = W_ih[j * NVT + t] + b_ih[j];
        if (j < 256) git += b_hh[j];          // fold b_hh for r,z only
        GIT[t * 384 + j] = f2bs(git);
    } else {
        TABB[j * NVT + t] = f2bs(G_s[j - 384]);
    }
}

// ---------------- Kernel H: partial histograms (4 chunks x 64 rows) ---------
__global__ void __launch_bounds__(256) hist_part(
    const int* __restrict__ node_types, const int* __restrict__ adj,
    unsigned char* __restrict__ cnt8)
{
    __shared__ unsigned tmask[NVT * 2];       // [t][word], 64 rows = 2 words
    const int blk = blockIdx.x;
    const int b = blk >> 2, c = blk & 3;
    const int tid = threadIdx.x;              // column v
    const int* adjb = adj + (size_t)b * NN * NN + c * 64 * NN;

    // column bits for 64 rows (coalesced: 1KB per row across the block)
    unsigned cb0 = 0, cb1 = 0;
    {
        int av[32];
        #pragma unroll
        for (int j = 0; j < 32; ++j) av[j] = adjb[j * NN + tid];
        #pragma unroll
        for (int j = 0; j < 32; ++j) cb0 |= ((unsigned)av[j]) << j;
        #pragma unroll
        for (int j = 0; j < 32; ++j) av[j] = adjb[(32 + j) * NN + tid];
        #pragma unroll
        for (int j = 0; j < 32; ++j) cb1 |= ((unsigned)av[j]) << j;
    }
    // per-type row bitmasks for this chunk
    if (tid < 64) {
        int t = tid >> 1, w2 = tid & 1;
        const int* ty = node_types + b * NN + c * 64 + w2 * 32;
        unsigned mw = 0;
        #pragma unroll
        for (int k = 0; k < 32; ++k)
            mw |= ((unsigned)(ty[k] == t)) << k;
        tmask[tid] = mw;
    }
    __syncthreads();

    // 32 popcount histcells, packed 4 u8 per u32 (chunk counts <= 64)
    unsigned outw[8];
    #pragma unroll
    for (int q = 0; q < 8; ++q) {
        unsigned w = 0;
        #pragma unroll
        for (int s = 0; s < 4; ++s) {
            int t = q * 4 + s;
            unsigned cnt = __popc(cb0 & tmask[2 * t]) + __popc(cb1 & tmask[2 * t + 1]);
            w |= cnt << (8 * s);
        }
        outw[q] = w;
    }
    uint4* dst = (uint4*)(cnt8 + ((size_t)blk * NN + tid) * 32);
    dst[0] = make_uint4(outw[0], outw[1], outw[2], outw[3]);
    dst[1] = make_uint4(outw[4], outw[5], outw[6], outw[7]);
}

// ---------------- Kernel M: combine + MFMA + GRU + readout ------------------
__global__ void __launch_bounds__(256) dvae_main(
    const int* __restrict__ node_types, const unsigned char* __restrict__ cnt8,
    const short* __restrict__ TABB, const short* __restrict__ GIT,
    const float* __restrict__ b_hh,
    const float* __restrict__ W1, const float* __restrict__ b1,
    const float* __restrict__ W2, const float* __restrict__ b2,
    float* __restrict__ out)
{
    __shared__ unsigned cntA[NN * 20];        // bf16 count pairs, row = 16 u32 + 4 pad
    __shared__ short GITs[NVT * 388];
    __shared__ int types_s[NN];
    __shared__ float hg_s[HS];

    const int b = blockIdx.x, tid = threadIdx.x;   // 256 threads = 4 waves
    const int wave = tid >> 6, lane = tid & 63;
    const int quad = lane >> 4, col = lane & 15;

    types_s[tid] = node_types[b * NN + tid];

    // combine 4 chunk partials for column tid (packed-byte adds; no carry: total <= 255)
    {
        uint4 a0, a1;
        {
            const uint4* s = (const uint4*)(cnt8 + ((size_t)(b * 4 + 0) * NN + tid) * 32);
            a0 = s[0]; a1 = s[1];
        }
        #pragma unroll
        for (int c = 1; c < 4; ++c) {
            const uint4* s = (const uint4*)(cnt8 + ((size_t)(b * 4 + c) * NN + tid) * 32);
            uint4 p0 = s[0], p1 = s[1];
            a0.x += p0.x; a0.y += p0.y; a0.z += p0.z; a0.w += p0.w;
            a1.x += p1.x; a1.y += p1.y; a1.z += p1.z; a1.w += p1.w;
        }
        unsigned acc8[8] = {a0.x, a0.y, a0.z, a0.w, a1.x, a1.y, a1.z, a1.w};
        #pragma unroll
        for (int q = 0; q < 8; ++q) {
            unsigned u = acc8[q];
            float f0 = (float)(u & 0xFF),         f1 = (float)((u >> 8) & 0xFF);
            float f2 = (float)((u >> 16) & 0xFF), f3 = (float)((u >> 24) & 0xFF);
            // counts <= 255: bf16 exact = top 16 bits of fp32
            cntA[tid * 20 + 2 * q]     = (__float_as_uint(f0) >> 16) | (__float_as_uint(f1) & 0xFFFF0000u);
            cntA[tid * 20 + 2 * q + 1] = (__float_as_uint(f2) >> 16) | (__float_as_uint(f3) & 0xFFFF0000u);
        }
    }

    // stage GIT (6144 uints) -> LDS rows stride 194 uints
    {
        const unsigned* src = (const unsigned*)GIT;
        unsigned* dst = (unsigned*)GITs;
        #pragma unroll
        for (int c = 0; c < 24; ++c) {
            int i = c * 256 + tid;
            int t = i / 192, j = i - t * 192;
            dst[t * 194 + j] = src[i];
        }
    }

    // B fragments: wave w owns h in [w*32, w*32+32): r,z,n gates + Hpre, 2 tiles each
    bf16x8 bfrag[8];
    #pragma unroll
    for (int i = 0; i < 8; ++i) {
        int gate = i >> 1, sub = (i & 1) * 16;
        int jb = (gate < 3 ? gate * 128 : 384) + wave * 32 + sub;
        bfrag[i] = *(const bf16x8*)(TABB + (jb + col) * 32 + quad * 8);
    }
    const int h0 = wave * 32 + col;
    const float bhn0 = b_hh[256 + h0], bhn1 = b_hh[256 + h0 + 16];
    float hg0 = 0.f, hg1 = 0.f;
    __syncthreads();

    // 16 m-tiles, barrier-free in-register GRU epilogue
    for (int m = 0; m < 16; ++m) {
        bf16x8 afrag = *(const bf16x8*)(cntA + (m * 16 + col) * 20 + quad * 4);
        f32x4 acc[8];
        #pragma unroll
        for (int i = 0; i < 8; ++i)
            acc[i] = __builtin_amdgcn_mfma_f32_16x16x32_bf16(
                afrag, bfrag[i], (f32x4){0.f, 0.f, 0.f, 0.f}, 0, 0, 0);
        // C/D: col = n (h), row = quad*4 + r (v)
        #pragma unroll
        for (int r = 0; r < 4; ++r) {
            int vv = m * 16 + quad * 4 + r;
            int tv = types_s[vv];
            float msk = (vv >= 1 && vv < NN - 1) ? 1.f : 0.f;
            const short* g = GITs + tv * 388;
            {   // h = h0
                float rr = sigm(bs2f(g[h0]) + acc[0][r]);
                float zz = sigm(bs2f(g[128 + h0]) + acc[2][r]);
                float x2 = bs2f(g[256 + h0]) + rr * (acc[4][r] + bhn0);
                float nt = 1.f - 2.f * __builtin_amdgcn_rcpf(1.f + __expf(2.f * x2));
                hg0 += msk * ((1.f - zz) * nt + zz * acc[6][r]);
            }
            {   // h = h0 + 16
                int h1 = h0 + 16;
                float rr = sigm(bs2f(g[h1]) + acc[1][r]);
                float zz = sigm(bs2f(g[128 + h1]) + acc[3][r]);
                float x2 = bs2f(g[256 + h1]) + rr * (acc[5][r] + bhn1);
                float nt = 1.f - 2.f * __builtin_amdgcn_rcpf(1.f + __expf(2.f * x2));
                hg1 += msk * ((1.f - zz) * nt + zz * acc[7][r]);
            }
        }
    }
    // reduce across quads (lane ^16, ^32 share h0)
    hg0 += __shfl_xor(hg0, 16); hg0 += __shfl_xor(hg0, 32);
    hg1 += __shfl_xor(hg1, 16); hg1 += __shfl_xor(hg1, 32);
    if (lane < 16) { hg_s[h0] = hg0; hg_s[h0 + 16] = hg1; }
    __syncthreads();

    // fused readout: mu (tid<64) / logvar (64<=tid<128)
    if (tid < 128) {
        int which = tid >> 6, zz = tid & 63;
        const float* W = which ? W2 : W1;
        float acc2 = which ? b2[zz] : b1[zz];
        const float4* Wv = (const float4*)(W + zz * HS);
        #pragma unroll
        for (int i = 0; i < 32; ++i) {
            float4 ww = Wv[i];
            acc2 += hg_s[4 * i] * ww.x + hg_s[4 * i + 1] * ww.y
                  + hg_s[4 * i + 2] * ww.z + hg_s[4 * i + 3] * ww.w;
        }
        out[which * 32768 + b * 64 + zz] = acc2;
    }
}

extern "C" void kernel_launch(void* const* d_in, const int* in_sizes, int n_in,
                              void* d_out, int out_size, void* d_ws, size_t ws_size,
                              hipStream_t stream)
{
    const int* node_types = (const int*)d_in[0];
    const int* adj        = (const int*)d_in[1];
    const float* W_ih = (const float*)d_in[2];
    const float* W_hh = (const float*)d_in[3];
    const float* b_ih = (const float*)d_in[4];
    const float* b_hh = (const float*)d_in[5];
    const float* Wg   = (const float*)d_in[6];
    const float* bg   = (const float*)d_in[7];
    const float* Wm   = (const float*)d_in[8];
    const float* W1   = (const float*)d_in[9];
    const float* b1   = (const float*)d_in[10];
    const float* W2   = (const float*)d_in[11];
    const float* b2   = (const float*)d_in[12];

    char* ws = (char*)d_ws;
    short* TABB = (short*)(ws + TABB_OFF);
    short* GIT  = (short*)(ws + GIT_OFF);
    unsigned char* cnt8 = (unsigned char*)(ws + CNT8_OFF);
    float* out  = (float*)d_out;

    build_tables<<<dim3(32), dim3(512), 0, stream>>>(W_ih, W_hh, b_ih, b_hh, Wg, bg, Wm, TABB, GIT);
    hist_part<<<dim3(2048), dim3(256), 0, stream>>>(node_types, adj, cnt8);
    dvae_main<<<dim3(512), dim3(256), 0, stream>>>(node_types, cnt8, TABB, GIT, b_hh, W1, b1, W2, b2, out);
}

// Round 6
// 251.211 us; speedup vs baseline: 1.0128x; 1.0128x over previous
//
#include <hip/hip_runtime.h>
#include <hip/hip_bf16.h>

#define HS 128
#define NVT 32
#define NN 256

typedef __attribute__((ext_vector_type(8))) short bf16x8;
typedef __attribute__((ext_vector_type(4))) short s16x4;
typedef __attribute__((ext_vector_type(4))) float f32x4;

// ws layout (bytes):
//   [0, 32768)       TABB bf16 [512][32]: rows 0..383 = GW[t][g] at [g][t]; rows 384..511 = G[t][h] at [384+h][t]
//   [32768, 65536)   GIT2 bf16 [32][128][4]: {gi_r+b, gi_z+b, gi_n, 0} per (t,h)
#define TABB_OFF 0
#define GIT2_OFF 32768

static __device__ __forceinline__ short f2bs(float f) {
    __hip_bfloat16 h = __float2bfloat16(f);
    short s; __builtin_memcpy(&s, &h, 2);
    return s;
}
static __device__ __forceinline__ float bs2f(short s) {
    __hip_bfloat16 h; __builtin_memcpy(&h, &s, 2);
    return __bfloat162float(h);
}
static __device__ __forceinline__ float sigm(float x) {
    return __builtin_amdgcn_rcpf(1.f + __expf(-x));
}

// ---------------- Kernel A: tiny tables (fp32 inputs) -----------------------
__global__ void __launch_bounds__(512) build_tables(
    const float* __restrict__ W_ih, const float* __restrict__ W_hh,
    const float* __restrict__ b_ih, const float* __restrict__ b_hh,
    const float* __restrict__ Wg,   const float* __restrict__ bg,
    const float* __restrict__ Wm,
    short* __restrict__ TABB, short* __restrict__ GIT2)
{
    __shared__ float G_s[HS];
    const int t = blockIdx.x;
    const int j = threadIdx.x;
    if (j < HS) {
        float x = Wg[j * NVT + t] + bg[j];
        G_s[j] = sigm(x) * Wm[j * NVT + t];
    }
    __syncthreads();
    if (j < 384) {
        float acc = 0.f;
        for (int h = 0; h < HS; ++h) acc += G_s[h] * W_hh[j * HS + h];
        TABB[j * NVT + t] = f2bs(acc);
        float git = W_ih[j * NVT + t] + b_ih[j];
        int gate = j >> 7, h = j & 127;
        if (gate < 2) git += b_hh[j];                 // fold b_hh for r,z only
        GIT2[(t * 128 + h) * 4 + gate] = f2bs(git);
    } else {
        TABB[j * NVT + t] = f2bs(G_s[j - 384]);       // G[t][h] at [384+h][t]
        GIT2[(t * 128 + (j - 384)) * 4 + 3] = 0;      // pad lane
    }
}

// ---------------- Kernel B: fused histogram + MFMA + GRU + readout ----------
__global__ void __launch_bounds__(256) dvae_fused(
    const int* __restrict__ node_types, const int* __restrict__ adj,
    const short* __restrict__ TABB, const short* __restrict__ GIT2,
    const float* __restrict__ b_hh,
    const float* __restrict__ W1, const float* __restrict__ b1,
    const float* __restrict__ W2, const float* __restrict__ b2,
    float* __restrict__ out)
{
    __shared__ unsigned cntA[NN * 20];    // 20 KB bf16 count pairs, row = 16 u32 + 4 pad
    __shared__ short GITs[NVT * 512];     // 32 KB [t][h][4] = {r,z,n,0}
    __shared__ unsigned pc[4 * NN * 8];   // 8 KB per-band partial counts [w][col][q]
    __shared__ unsigned tmask[NVT * 8];   // 1 KB [t][w8], w8 = row/32
    __shared__ int types_s[NN];
    __shared__ float hg_s[HS];

    const int b = blockIdx.x, tid = threadIdx.x;   // 256 threads = 4 waves
    const int wave = tid >> 6, lane = tid & 63;
    const int quad = lane >> 4, col = lane & 15;

    types_s[tid] = node_types[b * NN + tid];

    // stage GIT2 -> LDS (8192 u32, coalesced uint4)
    {
        const uint4* src = (const uint4*)GIT2;
        uint4* dst = (uint4*)GITs;
        #pragma unroll
        for (int i = 0; i < 8; ++i) dst[i * 256 + tid] = src[i * 256 + tid];
    }
    // B fragments: wave w owns h in [w*32, w*32+32): r,z,n gates + Hpre, 2 tiles each
    bf16x8 bfrag[8];
    #pragma unroll
    for (int i = 0; i < 8; ++i) {
        int gate = i >> 1, sub = (i & 1) * 16;
        int jb = (gate < 3 ? gate * 128 : 384) + wave * 32 + sub;
        bfrag[i] = *(const bf16x8*)(TABB + (jb + col) * 32 + quad * 8);
    }
    const int h0 = wave * 32 + col;
    const float bhn0 = b_hh[256 + h0], bhn1 = b_hh[256 + h0 + 16];
    __syncthreads();                      // types_s visible

    // per-type row bitmasks [t][w8]
    {
        int t = tid >> 3, w8 = tid & 7;
        const int* ty = types_s + w8 * 32;
        unsigned mw = 0;
        #pragma unroll
        for (int k = 0; k < 32; ++k) mw |= ((unsigned)(ty[k] == t)) << k;
        tmask[tid] = mw;
    }

    // ---- band load: wave w -> rows [w*64, w*64+64); lane l -> cols 4l..4l+3 ----
    // uint4 per (row, lane): 1 KB per wave-instruction, fully contiguous.
    const uint4* adjb = (const uint4*)(adj + (size_t)b * NN * NN) + wave * 64 * 64 + lane;
    unsigned cb0a = 0, cb0b = 0, cb1a = 0, cb1b = 0, cb2a = 0, cb2b = 0, cb3a = 0, cb3b = 0;
    #pragma unroll
    for (int half = 0; half < 2; ++half) {
        #pragma unroll
        for (int bb = 0; bb < 4; ++bb) {
            uint4 av[8];
            #pragma unroll
            for (int j = 0; j < 8; ++j) av[j] = adjb[(half * 32 + bb * 8 + j) * 64];
            #pragma unroll
            for (int j = 0; j < 8; ++j) {
                int sh = bb * 8 + j;
                if (half == 0) {
                    cb0a |= av[j].x << sh; cb1a |= av[j].y << sh;
                    cb2a |= av[j].z << sh; cb3a |= av[j].w << sh;
                } else {
                    cb0b |= av[j].x << sh; cb1b |= av[j].y << sh;
                    cb2b |= av[j].z << sh; cb3b |= av[j].w << sh;
                }
            }
        }
    }
    __syncthreads();                      // tmask ready (overlapped with loads)

    // ---- popcount vs 32 types -> u8-packed partial counts ----
    unsigned pcnt[4][8];
    #pragma unroll
    for (int k = 0; k < 4; ++k)
        #pragma unroll
        for (int q = 0; q < 8; ++q) pcnt[k][q] = 0;
    #pragma unroll
    for (int t = 0; t < 32; ++t) {
        unsigned tm0 = tmask[t * 8 + wave * 2];       // wave-uniform -> broadcast
        unsigned tm1 = tmask[t * 8 + wave * 2 + 1];
        unsigned sh = (unsigned)((t & 3) * 8);
        pcnt[0][t >> 2] += (__popc(cb0a & tm0) + __popc(cb0b & tm1)) << sh;
        pcnt[1][t >> 2] += (__popc(cb1a & tm0) + __popc(cb1b & tm1)) << sh;
        pcnt[2][t >> 2] += (__popc(cb2a & tm0) + __popc(cb2b & tm1)) << sh;
        pcnt[3][t >> 2] += (__popc(cb3a & tm0) + __popc(cb3b & tm1)) << sh;
    }
    {   // write partials: pc[(w*256 + col)*8 + q]
        uint4* p4 = (uint4*)pc;
        #pragma unroll
        for (int k = 0; k < 4; ++k) {
            int c = lane * 4 + k;
            p4[(wave * NN + c) * 2]     = make_uint4(pcnt[k][0], pcnt[k][1], pcnt[k][2], pcnt[k][3]);
            p4[(wave * NN + c) * 2 + 1] = make_uint4(pcnt[k][4], pcnt[k][5], pcnt[k][6], pcnt[k][7]);
        }
    }
    __syncthreads();

    // ---- combine 4 bands (packed-byte add; total <= 255, no carry) -> bf16 cntA ----
    {
        #pragma unroll
        for (int q = 0; q < 8; ++q) {
            unsigned u = pc[(0 * NN + tid) * 8 + q] + pc[(1 * NN + tid) * 8 + q]
                       + pc[(2 * NN + tid) * 8 + q] + pc[(3 * NN + tid) * 8 + q];
            float f0 = (float)(u & 0xFF),         f1 = (float)((u >> 8) & 0xFF);
            float f2 = (float)((u >> 16) & 0xFF), f3 = (float)((u >> 24) & 0xFF);
            // counts <= 255: bf16 exact = top 16 bits of fp32
            cntA[tid * 20 + 2 * q]     = (__float_as_uint(f0) >> 16) | (__float_as_uint(f1) & 0xFFFF0000u);
            cntA[tid * 20 + 2 * q + 1] = (__float_as_uint(f2) >> 16) | (__float_as_uint(f3) & 0xFFFF0000u);
        }
    }
    __syncthreads();

    // ---- 16 m-tiles, barrier-free in-register GRU epilogue ----
    float hg0 = 0.f, hg1 = 0.f;
    for (int m = 0; m < 16; ++m) {
        bf16x8 afrag = *(const bf16x8*)(cntA + (m * 16 + col) * 20 + quad * 4);
        f32x4 acc[8];
        #pragma unroll
        for (int i = 0; i < 8; ++i)
            acc[i] = __builtin_amdgcn_mfma_f32_16x16x32_bf16(
                afrag, bfrag[i], (f32x4){0.f, 0.f, 0.f, 0.f}, 0, 0, 0);
        // C/D: col = n (h), row = quad*4 + r (v)
        #pragma unroll
        for (int r = 0; r < 4; ++r) {
            int vv = m * 16 + quad * 4 + r;
            int tv = types_s[vv];
            float msk = (vv >= 1 && vv < NN - 1) ? 1.f : 0.f;
            {   // h = h0
                s16x4 gg = *(const s16x4*)(GITs + (tv * 128 + h0) * 4);
                float rr = sigm(bs2f(gg[0]) + acc[0][r]);
                float zz = sigm(bs2f(gg[1]) + acc[2][r]);
                float x2 = bs2f(gg[2]) + rr * (acc[4][r] + bhn0);
                float nt = 1.f - 2.f * __builtin_amdgcn_rcpf(1.f + __expf(2.f * x2));
                hg0 += msk * ((1.f - zz) * nt + zz * acc[6][r]);
            }
            {   // h = h0 + 16
                s16x4 gg = *(const s16x4*)(GITs + (tv * 128 + h0 + 16) * 4);
                float rr = sigm(bs2f(gg[0]) + acc[1][r]);
                float zz = sigm(bs2f(gg[1]) + acc[3][r]);
                float x2 = bs2f(gg[2]) + rr * (acc[5][r] + bhn1);
                float nt = 1.f - 2.f * __builtin_amdgcn_rcpf(1.f + __expf(2.f * x2));
                hg1 += msk * ((1.f - zz) * nt + zz * acc[7][r]);
            }
        }
    }
    // reduce across quads (lane ^16, ^32 share h0)
    hg0 += __shfl_xor(hg0, 16); hg0 += __shfl_xor(hg0, 32);
    hg1 += __shfl_xor(hg1, 16); hg1 += __shfl_xor(hg1, 32);
    if (lane < 16) { hg_s[h0] = hg0; hg_s[h0 + 16] = hg1; }
    __syncthreads();

    // fused readout: mu (tid<64) / logvar (64<=tid<128)
    if (tid < 128) {
        int which = tid >> 6, zz = tid & 63;
        const float* W = which ? W2 : W1;
        float acc2 = which ? b2[zz] : b1[zz];
        const float4* Wv = (const float4*)(W + zz * HS);
        #pragma unroll
        for (int i = 0; i < 32; ++i) {
            float4 ww = Wv[i];
            acc2 += hg_s[4 * i] * ww.x + hg_s[4 * i + 1] * ww.y
                  + hg_s[4 * i + 2] * ww.z + hg_s[4 * i + 3] * ww.w;
        }
        out[which * 32768 + b * 64 + zz] = acc2;
    }
}

extern "C" void kernel_launch(void* const* d_in, const int* in_sizes, int n_in,
                              void* d_out, int out_size, void* d_ws, size_t ws_size,
                              hipStream_t stream)
{
    const int* node_types = (const int*)d_in[0];
    const int* adj        = (const int*)d_in[1];
    const float* W_ih = (const float*)d_in[2];
    const float* W_hh = (const float*)d_in[3];
    const float* b_ih = (const float*)d_in[4];
    const float* b_hh = (const float*)d_in[5];
    const float* Wg   = (const float*)d_in[6];
    const float* bg   = (const float*)d_in[7];
    const float* Wm   = (const float*)d_in[8];
    const float* W1   = (const float*)d_in[9];
    const float* b1   = (const float*)d_in[10];
    const float* W2   = (const float*)d_in[11];
    const float* b2   = (const float*)d_in[12];

    char* ws = (char*)d_ws;
    short* TABB = (short*)(ws + TABB_OFF);
    short* GIT2 = (short*)(ws + GIT2_OFF);
    float* out  = (float*)d_out;

    build_tables<<<dim3(32), dim3(512), 0, stream>>>(W_ih, W_hh, b_ih, b_hh, Wg, bg, Wm, TABB, GIT2);
    dvae_fused<<<dim3(512), dim3(256), 0, stream>>>(node_types, adj, TABB, GIT2, b_hh, W1, b1, W2, b2, out);
}

// Round 7
// 245.984 us; speedup vs baseline: 1.0343x; 1.0213x over previous
//
#include <hip/hip_runtime.h>
#include <hip/hip_bf16.h>

#define HS 128
#define NVT 32
#define NN 256

typedef __attribute__((ext_vector_type(8))) short bf16x8;
typedef __attribute__((ext_vector_type(4))) short s16x4;
typedef __attribute__((ext_vector_type(4))) float f32x4;

// ws layout (bytes):
//   [0, 32768)       TABB bf16 [512][32]: rows 0..383 = GW[t][g] at [g][t]; rows 384..511 = G[t][h] at [384+h][t]
//   [32768, 65536)   GIT2 bf16 [32][128][4]: {gi_r+b, gi_z+b, gi_n, 0}
//   [65536, 8454144) cnt u32 [512][256][16]  bf16 count pairs
#define TABB_OFF 0
#define GIT2_OFF 32768
#define CNT_OFF  65536

static __device__ __forceinline__ short f2bs(float f) {
    __hip_bfloat16 h = __float2bfloat16(f);
    short s; __builtin_memcpy(&s, &h, 2);
    return s;
}
static __device__ __forceinline__ float bs2f(short s) {
    __hip_bfloat16 h; __builtin_memcpy(&h, &s, 2);
    return __bfloat162float(h);
}
static __device__ __forceinline__ float sigm(float x) {
    return __builtin_amdgcn_rcpf(1.f + __expf(-x));
}
// async global->LDS, 16B per lane; LDS dest = wave-uniform base + lane*16
static __device__ __forceinline__ void lds_load16(const void* g, void* l) {
    __builtin_amdgcn_global_load_lds(
        (const __attribute__((address_space(1))) unsigned int*)g,
        (__attribute__((address_space(3))) unsigned int*)l, 16, 0, 0);
}

// ---------------- Kernel A: tiny tables (fp32 inputs) -----------------------
__global__ void __launch_bounds__(512) build_tables(
    const float* __restrict__ W_ih, const float* __restrict__ W_hh,
    const float* __restrict__ b_ih, const float* __restrict__ b_hh,
    const float* __restrict__ Wg,   const float* __restrict__ bg,
    const float* __restrict__ Wm,
    short* __restrict__ TABB, short* __restrict__ GIT2)
{
    __shared__ float G_s[HS];
    const int t = blockIdx.x;
    const int j = threadIdx.x;
    if (j < HS) {
        float x = Wg[j * NVT + t] + bg[j];
        G_s[j] = sigm(x) * Wm[j * NVT + t];
    }
    __syncthreads();
    if (j < 384) {
        float acc = 0.f;
        for (int h = 0; h < HS; ++h) acc += G_s[h] * W_hh[j * HS + h];
        TABB[j * NVT + t] = f2bs(acc);
        float git = W_ih[j * NVT + t] + b_ih[j];
        int gate = j >> 7, h = j & 127;
        if (gate < 2) git += b_hh[j];                 // fold b_hh for r,z only
        GIT2[(t * 128 + h) * 4 + gate] = f2bs(git);
    } else {
        TABB[j * NVT + t] = f2bs(G_s[j - 384]);       // G[t][h] at [384+h][t]
        GIT2[(t * 128 + (j - 384)) * 4 + 3] = 0;      // pad lane
    }
}

// ---------------- Kernel H: histogram via async LDS staging -----------------
__global__ void __launch_bounds__(256) hist(
    const int* __restrict__ node_types, const int* __restrict__ adj,
    unsigned* __restrict__ cnt_out)
{
    __shared__ int tile[64 * NN];         // 64 KB: 64 rows x 256 cols
    __shared__ unsigned tmask[NVT * 8];   // [t][w8]
    __shared__ int types_s[NN];

    const int b = blockIdx.x, tid = threadIdx.x;   // 256 thr = 4 waves
    const int wave = tid >> 6, lane = tid & 63;

    types_s[tid] = node_types[b * NN + tid];
    __syncthreads();
    {   // per-type row bitmasks over all 256 rows
        int t = tid >> 3, w8 = tid & 7;
        const int* ty = types_s + w8 * 32;
        unsigned mw = 0;
        #pragma unroll
        for (int k = 0; k < 32; ++k) mw |= ((unsigned)(ty[k] == t)) << k;
        tmask[tid] = mw;                  // visible after the in-loop barrier
    }

    const char* gb = (const char*)(adj + (size_t)b * NN * NN);
    unsigned pcnt[8] = {0, 0, 0, 0, 0, 0, 0, 0};   // 32 u8 counters

    for (int tk = 0; tk < 4; ++tk) {
        // stage 64 rows (64 KB): wave w issues rows w*16..w*16+16, 1 KB per instr,
        // zero VGPR results -> 16 KB in flight per wave
        #pragma unroll
        for (int j = 0; j < 16; ++j) {
            int r = wave * 16 + j;
            lds_load16(gb + (size_t)(tk * 64 + r) * 1024 + lane * 16, &tile[r * NN]);
        }
        __syncthreads();                  // vmcnt drain: tile ready (+ tmask on tk=0)
        // column bitmask: lanes read consecutive dwords -> 2-way bank alias (free)
        unsigned w0 = 0, w1 = 0;
        #pragma unroll
        for (int rr = 0; rr < 32; ++rr) w0 |= ((unsigned)tile[rr * NN + tid]) << rr;
        #pragma unroll
        for (int rr = 0; rr < 32; ++rr) w1 |= ((unsigned)tile[(32 + rr) * NN + tid]) << rr;
        #pragma unroll
        for (int t = 0; t < NVT; ++t) {   // tmask reads wave-uniform -> broadcast
            unsigned c = __popc(w0 & tmask[t * 8 + 2 * tk])
                       + __popc(w1 & tmask[t * 8 + 2 * tk + 1]);
            pcnt[t >> 2] += c << ((t & 3) * 8);
        }
        __syncthreads();                  // all reads done before overwrite
    }

    // counts <= 255: bf16 exact = top 16 bits of fp32
    unsigned* dst = cnt_out + ((size_t)b * NN + tid) * 16;
    #pragma unroll
    for (int q = 0; q < 8; ++q) {
        unsigned u = pcnt[q];
        float f0 = (float)(u & 0xFF),         f1 = (float)((u >> 8) & 0xFF);
        float f2 = (float)((u >> 16) & 0xFF), f3 = (float)((u >> 24) & 0xFF);
        dst[2 * q]     = (__float_as_uint(f0) >> 16) | (__float_as_uint(f1) & 0xFFFF0000u);
        dst[2 * q + 1] = (__float_as_uint(f2) >> 16) | (__float_as_uint(f3) & 0xFFFF0000u);
    }
}

// ---------------- Kernel M: MFMA + GRU + readout ----------------------------
__global__ void __launch_bounds__(256) dvae_main(
    const int* __restrict__ node_types, const unsigned* __restrict__ cntw,
    const short* __restrict__ TABB, const short* __restrict__ GIT2,
    const float* __restrict__ b_hh,
    const float* __restrict__ W1, const float* __restrict__ b1,
    const float* __restrict__ W2, const float* __restrict__ b2,
    float* __restrict__ out)
{
    __shared__ unsigned cntA[NN * 20];    // 20 KB bf16 count pairs, row = 16 u32 + 4 pad
    __shared__ short GITs[NVT * 512];     // 32 KB [t][h][4] = {r,z,n,0}
    __shared__ int types_s[NN];
    __shared__ float hg_s[HS];

    const int b = blockIdx.x, tid = threadIdx.x;   // 256 thr = 4 waves
    const int wave = tid >> 6, lane = tid & 63;
    const int quad = lane >> 4, col = lane & 15;

    types_s[tid] = node_types[b * NN + tid];

    // load counts (16 u32 per row) -> padded LDS rows
    {
        const uint4* src = (const uint4*)(cntw + ((size_t)b * NN + tid) * 16);
        uint4* drow = (uint4*)(cntA + tid * 20);   // 80 B stride, 16B aligned
        #pragma unroll
        for (int c = 0; c < 4; ++c) drow[c] = src[c];
    }
    // stage GIT2 -> LDS (8192 u32, coalesced uint4)
    {
        const uint4* src = (const uint4*)GIT2;
        uint4* dst = (uint4*)GITs;
        #pragma unroll
        for (int i = 0; i < 8; ++i) dst[i * 256 + tid] = src[i * 256 + tid];
    }
    // B fragments: wave w owns h in [w*32, w*32+32): r,z,n gates + Hpre, 2 tiles each
    bf16x8 bfrag[8];
    #pragma unroll
    for (int i = 0; i < 8; ++i) {
        int gate = i >> 1, sub = (i & 1) * 16;
        int jb = (gate < 3 ? gate * 128 : 384) + wave * 32 + sub;
        bfrag[i] = *(const bf16x8*)(TABB + (jb + col) * 32 + quad * 8);
    }
    const int h0 = wave * 32 + col;
    const float bhn0 = b_hh[256 + h0], bhn1 = b_hh[256 + h0 + 16];
    float hg0 = 0.f, hg1 = 0.f;
    __syncthreads();

    // 16 m-tiles, barrier-free in-register GRU epilogue
    for (int m = 0; m < 16; ++m) {
        bf16x8 afrag = *(const bf16x8*)(cntA + (m * 16 + col) * 20 + quad * 4);
        f32x4 acc[8];
        #pragma unroll
        for (int i = 0; i < 8; ++i)
            acc[i] = __builtin_amdgcn_mfma_f32_16x16x32_bf16(
                afrag, bfrag[i], (f32x4){0.f, 0.f, 0.f, 0.f}, 0, 0, 0);
        // C/D: col = n (h), row = quad*4 + r (v)
        #pragma unroll
        for (int r = 0; r < 4; ++r) {
            int vv = m * 16 + quad * 4 + r;
            int tv = types_s[vv];
            float msk = (vv >= 1 && vv < NN - 1) ? 1.f : 0.f;
            {   // h = h0
                s16x4 gg = *(const s16x4*)(GITs + (tv * 128 + h0) * 4);
                float rr = sigm(bs2f(gg[0]) + acc[0][r]);
                float zz = sigm(bs2f(gg[1]) + acc[2][r]);
                float x2 = bs2f(gg[2]) + rr * (acc[4][r] + bhn0);
                float nt = 1.f - 2.f * __builtin_amdgcn_rcpf(1.f + __expf(2.f * x2));
                hg0 += msk * ((1.f - zz) * nt + zz * acc[6][r]);
            }
            {   // h = h0 + 16
                s16x4 gg = *(const s16x4*)(GITs + (tv * 128 + h0 + 16) * 4);
                float rr = sigm(bs2f(gg[0]) + acc[1][r]);
                float zz = sigm(bs2f(gg[1]) + acc[3][r]);
                float x2 = bs2f(gg[2]) + rr * (acc[5][r] + bhn1);
                float nt = 1.f - 2.f * __builtin_amdgcn_rcpf(1.f + __expf(2.f * x2));
                hg1 += msk * ((1.f - zz) * nt + zz * acc[7][r]);
            }
        }
    }
    // reduce across quads (lane ^16, ^32 share h0)
    hg0 += __shfl_xor(hg0, 16); hg0 += __shfl_xor(hg0, 32);
    hg1 += __shfl_xor(hg1, 16); hg1 += __shfl_xor(hg1, 32);
    if (lane < 16) { hg_s[h0] = hg0; hg_s[h0 + 16] = hg1; }
    __syncthreads();

    // fused readout: mu (tid<64) / logvar (64<=tid<128)
    if (tid < 128) {
        int which = tid >> 6, zz = tid & 63;
        const float* W = which ? W2 : W1;
        float acc2 = which ? b2[zz] : b1[zz];
        const float4* Wv = (const float4*)(W + zz * HS);
        #pragma unroll
        for (int i = 0; i < 32; ++i) {
            float4 ww = Wv[i];
            acc2 += hg_s[4 * i] * ww.x + hg_s[4 * i + 1] * ww.y
                  + hg_s[4 * i + 2] * ww.z + hg_s[4 * i + 3] * ww.w;
        }
        out[which * 32768 + b * 64 + zz] = acc2;
    }
}

extern "C" void kernel_launch(void* const* d_in, const int* in_sizes, int n_in,
                              void* d_out, int out_size, void* d_ws, size_t ws_size,
                              hipStream_t stream)
{
    const int* node_types = (const int*)d_in[0];
    const int* adj        = (const int*)d_in[1];
    const float* W_ih = (const float*)d_in[2];
    const float* W_hh = (const float*)d_in[3];
    const float* b_ih = (const float*)d_in[4];
    const float* b_hh = (const float*)d_in[5];
    const float* Wg   = (const float*)d_in[6];
    const float* bg   = (const float*)d_in[7];
    const float* Wm   = (const float*)d_in[8];
    const float* W1   = (const float*)d_in[9];
    const float* b1   = (const float*)d_in[10];
    const float* W2   = (const float*)d_in[11];
    const float* b2   = (const float*)d_in[12];

    char* ws = (char*)d_ws;
    short* TABB = (short*)(ws + TABB_OFF);
    short* GIT2 = (short*)(ws + GIT2_OFF);
    unsigned* cnt = (unsigned*)(ws + CNT_OFF);
    float* out  = (float*)d_out;

    build_tables<<<dim3(32), dim3(512), 0, stream>>>(W_ih, W_hh, b_ih, b_hh, Wg, bg, Wm, TABB, GIT2);
    hist<<<dim3(512), dim3(256), 0, stream>>>(node_types, adj, cnt);
    dvae_main<<<dim3(512), dim3(256), 0, stream>>>(node_types, cnt, TABB, GIT2, b_hh, W1, b1, W2, b2, out);
}